// Round 12
// baseline (55.214 us; speedup 1.0000x reference)
//
#include <hip/hip_runtime.h>

typedef float f32x2 __attribute__((ext_vector_type(2)));
typedef float f32x4 __attribute__((ext_vector_type(4)));
typedef short short8 __attribute__((ext_vector_type(8)));  // 8 x bf16 bits

static __device__ __forceinline__ unsigned short f2bf(float f) {
    __bf16 h = (__bf16)f;
    return __builtin_bit_cast(unsigned short, h);
}

// ---------------------------------------------------------------------------
// Kernel A: contract TT cores into dense TRANSPOSED bf16 weights.
//   WdT[j][pos(i)] = Wd[i][j]  (pos = k-slot permutation matching the fused
//   kernel's dense x loads; dot products are slot-permutation invariant).
//   WuT[d][k] = Wu[k][d].
// ---------------------------------------------------------------------------
__global__ __launch_bounds__(256) void tt_build_w_kernel(
    const float* __restrict__ d1, const float* __restrict__ d2, const float* __restrict__ d3,
    const float* __restrict__ u1, const float* __restrict__ u2, const float* __restrict__ u3,
    unsigned short* __restrict__ WdT, unsigned short* __restrict__ WuT)
{
    int t = blockIdx.x * 256 + threadIdx.x;
    if (t < 65536) {
        int j = t >> 10, i = t & 1023;
        int i1 = i >> 7, i2 = (i >> 3) & 15, i3 = i & 7;
        int j1 = j >> 4, j2 = (j >> 2) & 3, j3 = j & 3;
        float t3[8];
#pragma unroll
        for (int b = 0; b < 8; ++b) t3[b] = d3[(b * 8 + i3) * 4 + j3];
        float wsum = 0.f;
#pragma unroll
        for (int a = 0; a < 8; ++a) {
            float va = d1[(i1 * 4 + j1) * 8 + a];
            const float* p2 = d2 + ((a * 16 + i2) * 4 + j2) * 8;
            float wa = 0.f;
#pragma unroll
            for (int b = 0; b < 8; ++b) wa = fmaf(p2[b], t3[b], wa);
            wsum = fmaf(va, wa, wsum);
        }
        int g = i & 31;
        int h = g >> 4, kgg = (g >> 2) & 3, e = g & 3;
        int pos = (i & ~31) | (kgg * 8 + h * 4 + e);
        WdT[j * 1024 + pos] = f2bf(wsum);
    } else {
        int t2 = t - 65536;
        int d = t2 >> 6, k = t2 & 63;
        int k1 = k >> 4, k2 = (k >> 2) & 3, k3 = k & 3;
        int o1 = d >> 7, o2 = (d >> 3) & 15, o3 = d & 7;
        float t3[8];
#pragma unroll
        for (int b = 0; b < 8; ++b) t3[b] = u3[(b * 4 + k3) * 8 + o3];
        float wsum = 0.f;
#pragma unroll
        for (int a = 0; a < 8; ++a) {
            float va = u1[(k1 * 8 + o1) * 8 + a];
            const float* p2 = u2 + ((a * 4 + k2) * 16 + o2) * 8;
            float wa = 0.f;
#pragma unroll
            for (int b = 0; b < 8; ++b) wa = fmaf(p2[b], t3[b], wa);
            wsum = fmaf(va, wa, wsum);
        }
        WuT[d * 64 + k] = f2bf(wsum);
    }
}

// ---------------------------------------------------------------------------
// Fused main kernel. 512 blocks x 256 thr (4 waves). Block owns 2 row-tiles.
// Phase A: wave (pair,half) computes z-partial over K in [512*half, +512):
//   16 k-steps, register double-buffer; per step {2 x-loads + 4 WdT-loads}
//   pinned asm; counted vmcnt(6) (12 VMEM = 12KB/wave posted continuously,
//   x(HBM) and WdT(L2) drain concurrently; never vmcnt(0) until the tail).
//   Full 16x64 z-tile stays in 16 acc VGPRs (no split-K across waves).
// One barrier: pairwise half-reduce via LDS red[pair][half][16][68].
// Phase B: wave (pair, colhalf) builds z B-frags (sum halves + bias + relu,
//   in-register) and streams 32 col-tiles: 2 WuT L2 loads + 2 swapped MFMA
//   (A=WuT frag, B=z frag; D: col=lane&15->row m, row=kg*4+r->col d) ->
//   dwordx4 y stores, fire-and-forget, no barrier.
// ---------------------------------------------------------------------------
__global__ __launch_bounds__(256, 2) void tt_fused_kernel(
    const float* __restrict__ x, const unsigned short* __restrict__ WdT,
    const unsigned short* __restrict__ WuT, const float* __restrict__ bd,
    const float* __restrict__ bu, float* __restrict__ y)
{
    __shared__ float red[2][2][16][68];   // [pair][khalf][m][j+pad] = 34.8 KB
    const int t = threadIdx.x;
    const int lane = t & 63;
    const int w = t >> 6;          // 0..3
    const int l15 = lane & 15;
    const int kg = lane >> 4;      // 0..3
    const int pair = w >> 1;
    const int half = w & 1;
    const int tile = blockIdx.x * 2 + pair;
    const int kb = half * 512;

    const float* xp = x + (size_t)(tile * 16 + l15) * 1024 + kb + kg * 4;
    const unsigned short* wq0 = WdT + l15 * 1024 + kb + kg * 8;
    const unsigned short* wq1 = wq0 + 16 * 1024;
    const unsigned short* wq2 = wq0 + 32 * 1024;
    const unsigned short* wq3 = wq0 + 48 * 1024;

    f32x4 xb[2][2];
    short8 wb[2][4];
    f32x4 acc[4] = {{0.f, 0.f, 0.f, 0.f}, {0.f, 0.f, 0.f, 0.f},
                    {0.f, 0.f, 0.f, 0.f}, {0.f, 0.f, 0.f, 0.f}};

    // issue step s's 6 loads into buffer B (XO0=s*128, XO1=s*128+64, WO=s*64)
#define ISSUE(B, XO0, XO1, WO)                                                                          \
    asm volatile("global_load_dwordx4 %0, %1, off offset:" #XO0 : "=v"(xb[B][0]) : "v"(xp)  : "memory"); \
    asm volatile("global_load_dwordx4 %0, %1, off offset:" #XO1 : "=v"(xb[B][1]) : "v"(xp)  : "memory"); \
    asm volatile("global_load_dwordx4 %0, %1, off offset:" #WO  : "=v"(wb[B][0]) : "v"(wq0) : "memory"); \
    asm volatile("global_load_dwordx4 %0, %1, off offset:" #WO  : "=v"(wb[B][1]) : "v"(wq1) : "memory"); \
    asm volatile("global_load_dwordx4 %0, %1, off offset:" #WO  : "=v"(wb[B][2]) : "v"(wq2) : "memory"); \
    asm volatile("global_load_dwordx4 %0, %1, off offset:" #WO  : "=v"(wb[B][3]) : "v"(wq3) : "memory");

    // entering step s: L(s)+L(s+1) = 12 outstanding; vmcnt(6) -> L(s) ready
#define COMPUTE(B, WN) do {                                                           \
    asm volatile("s_waitcnt vmcnt(" #WN ")" ::: "memory");                            \
    __builtin_amdgcn_sched_barrier(0);                                                \
    union { short8 v; unsigned short e[8]; } a;                                       \
    a.e[0] = f2bf(xb[B][0][0]); a.e[1] = f2bf(xb[B][0][1]);                           \
    a.e[2] = f2bf(xb[B][0][2]); a.e[3] = f2bf(xb[B][0][3]);                           \
    a.e[4] = f2bf(xb[B][1][0]); a.e[5] = f2bf(xb[B][1][1]);                           \
    a.e[6] = f2bf(xb[B][1][2]); a.e[7] = f2bf(xb[B][1][3]);                           \
    acc[0] = __builtin_amdgcn_mfma_f32_16x16x32_bf16(a.v, wb[B][0], acc[0], 0, 0, 0); \
    acc[1] = __builtin_amdgcn_mfma_f32_16x16x32_bf16(a.v, wb[B][1], acc[1], 0, 0, 0); \
    acc[2] = __builtin_amdgcn_mfma_f32_16x16x32_bf16(a.v, wb[B][2], acc[2], 0, 0, 0); \
    acc[3] = __builtin_amdgcn_mfma_f32_16x16x32_bf16(a.v, wb[B][3], acc[3], 0, 0, 0); \
} while (0)

    ISSUE(0, 0, 64, 0)          // L0
    ISSUE(1, 128, 192, 64)      // L1
    COMPUTE(0, 6); ISSUE(0, 256, 320, 128)     // s=0,  L2
    COMPUTE(1, 6); ISSUE(1, 384, 448, 192)     // s=1,  L3
    COMPUTE(0, 6); ISSUE(0, 512, 576, 256)     // s=2,  L4
    COMPUTE(1, 6); ISSUE(1, 640, 704, 320)     // s=3,  L5
    COMPUTE(0, 6); ISSUE(0, 768, 832, 384)     // s=4,  L6
    COMPUTE(1, 6); ISSUE(1, 896, 960, 448)     // s=5,  L7
    COMPUTE(0, 6); ISSUE(0, 1024, 1088, 512)   // s=6,  L8
    COMPUTE(1, 6); ISSUE(1, 1152, 1216, 576)   // s=7,  L9
    COMPUTE(0, 6); ISSUE(0, 1280, 1344, 640)   // s=8,  L10
    COMPUTE(1, 6); ISSUE(1, 1408, 1472, 704)   // s=9,  L11
    COMPUTE(0, 6); ISSUE(0, 1536, 1600, 768)   // s=10, L12
    COMPUTE(1, 6); ISSUE(1, 1664, 1728, 832)   // s=11, L13
    COMPUTE(0, 6); ISSUE(0, 1792, 1856, 896)   // s=12, L14
    COMPUTE(1, 6); ISSUE(1, 1920, 1984, 960)   // s=13, L15
    COMPUTE(0, 6);                             // s=14 (L15 stays in flight)
    COMPUTE(1, 0);                             // s=15 (drain)
#undef ISSUE
#undef COMPUTE

    // acc[ct][r] = z-partial[m=kg*4+r][j=ct*16+l15] -> red (2-way bank, free)
#pragma unroll
    for (int ct = 0; ct < 4; ++ct)
#pragma unroll
        for (int r = 0; r < 4; ++r)
            red[pair][half][kg * 4 + r][ct * 16 + l15] = acc[ct][r];
    __syncthreads();

    // -------------------- phase B: wave = (pair, col-half) -----------------
    const int cb = half * 512;
    const float* r0 = &red[pair][0][l15][0];
    const float* r1 = &red[pair][1][l15][0];
    f32x4 s00 = *reinterpret_cast<const f32x4*>(r0 + kg * 8);
    f32x4 s01 = *reinterpret_cast<const f32x4*>(r0 + kg * 8 + 4);
    f32x4 s02 = *reinterpret_cast<const f32x4*>(r0 + 32 + kg * 8);
    f32x4 s03 = *reinterpret_cast<const f32x4*>(r0 + 32 + kg * 8 + 4);
    f32x4 s10 = *reinterpret_cast<const f32x4*>(r1 + kg * 8);
    f32x4 s11 = *reinterpret_cast<const f32x4*>(r1 + kg * 8 + 4);
    f32x4 s12 = *reinterpret_cast<const f32x4*>(r1 + 32 + kg * 8);
    f32x4 s13 = *reinterpret_cast<const f32x4*>(r1 + 32 + kg * 8 + 4);
    f32x4 b0 = *reinterpret_cast<const f32x4*>(bd + kg * 8);
    f32x4 b1 = *reinterpret_cast<const f32x4*>(bd + kg * 8 + 4);
    f32x4 b2 = *reinterpret_cast<const f32x4*>(bd + 32 + kg * 8);
    f32x4 b3 = *reinterpret_cast<const f32x4*>(bd + 32 + kg * 8 + 4);

    union { short8 v; unsigned short e[8]; } az0u, az1u;
#pragma unroll
    for (int e = 0; e < 4; ++e) {
        float z0 = s00[e] + s10[e] + b0[e]; z0 = z0 > 0.f ? z0 : 0.f;
        float z1 = s01[e] + s11[e] + b1[e]; z1 = z1 > 0.f ? z1 : 0.f;
        float z2 = s02[e] + s12[e] + b2[e]; z2 = z2 > 0.f ? z2 : 0.f;
        float z3 = s03[e] + s13[e] + b3[e]; z3 = z3 > 0.f ? z3 : 0.f;
        az0u.e[e] = f2bf(z0); az0u.e[e + 4] = f2bf(z1);
        az1u.e[e] = f2bf(z2); az1u.e[e + 4] = f2bf(z3);
    }
    const short8 az0 = az0u.v, az1 = az1u.v;

    const unsigned short* wup = WuT + (size_t)(cb + l15) * 64 + kg * 8;
    const float* bup = bu + cb + kg * 4;
    float* yp = y + (size_t)(tile * 16 + l15) * 1024 + cb + kg * 4;
#pragma unroll
    for (int ct = 0; ct < 32; ++ct) {
        short8 wa0 = *reinterpret_cast<const short8*>(wup + ct * 1024);
        short8 wa1 = *reinterpret_cast<const short8*>(wup + ct * 1024 + 32);
        f32x4 c = {0.f, 0.f, 0.f, 0.f};
        c = __builtin_amdgcn_mfma_f32_16x16x32_bf16(wa0, az0, c, 0, 0, 0);
        c = __builtin_amdgcn_mfma_f32_16x16x32_bf16(wa1, az1, c, 0, 0, 0);
        f32x4 bv = *reinterpret_cast<const f32x4*>(bup + ct * 16);
        f32x4 o;
#pragma unroll
        for (int r = 0; r < 4; ++r) o[r] = c[r] + bv[r];
        // lane holds y[tile*16+l15][cb + ct*16 + kg*4 + r]
        *reinterpret_cast<f32x4*>(yp + ct * 16) = o;
    }
}

extern "C" void kernel_launch(void* const* d_in, const int* in_sizes, int n_in,
                              void* d_out, int out_size, void* d_ws, size_t ws_size,
                              hipStream_t stream) {
    const float* x  = (const float*)d_in[0];
    const float* d1 = (const float*)d_in[1];
    const float* d2 = (const float*)d_in[2];
    const float* d3 = (const float*)d_in[3];
    const float* u1 = (const float*)d_in[4];
    const float* u2 = (const float*)d_in[5];
    const float* u3 = (const float*)d_in[6];
    const float* bd = (const float*)d_in[7];
    const float* bu = (const float*)d_in[8];
    float* y = (float*)d_out;
    unsigned short* WdT = (unsigned short*)d_ws;   // 64x1024 bf16 (128 KB)
    unsigned short* WuT = WdT + 65536;             // 1024x64 bf16 (128 KB)

    hipLaunchKernelGGL(tt_build_w_kernel, dim3(512), dim3(256), 0, stream,
                       d1, d2, d3, u1, u2, u3, WdT, WuT);
    hipLaunchKernelGGL(tt_fused_kernel, dim3(512), dim3(256), 0, stream,
                       x, WdT, WuT, bd, bu, y);
}

// Round 13
// 54.842 us; speedup vs baseline: 1.0068x; 1.0068x over previous
//
#include <hip/hip_runtime.h>

typedef float f32x2 __attribute__((ext_vector_type(2)));
typedef float f32x4 __attribute__((ext_vector_type(4)));
typedef short short8 __attribute__((ext_vector_type(8)));  // 8 x bf16 bits

static __device__ __forceinline__ unsigned short f2bf(float f) {
    __bf16 h = (__bf16)f;
    return __builtin_bit_cast(unsigned short, h);
}

// async global->LDS, 16B/lane: lane i of the wave fetches g + i*16 bytes and
// HW writes LDS at l + i*16 (l must be wave-uniform). Proven m97 load path.
static __device__ __forceinline__ void gload_lds16(const float* g, float* l) {
    __builtin_amdgcn_global_load_lds(
        (const __attribute__((address_space(1))) void*)g,
        (__attribute__((address_space(3))) void*)l, 16, 0, 0);
}

// ---------------------------------------------------------------------------
// Kernel A: contract TT cores into dense TRANSPOSED bf16 weights.
//   WdT[j][i] = Wd[i][j]  (natural k order; x is consumed in natural order)
//   WuT[d][k] = Wu[k][d]
// ---------------------------------------------------------------------------
__global__ __launch_bounds__(256) void tt_build_w_kernel(
    const float* __restrict__ d1, const float* __restrict__ d2, const float* __restrict__ d3,
    const float* __restrict__ u1, const float* __restrict__ u2, const float* __restrict__ u3,
    unsigned short* __restrict__ WdT, unsigned short* __restrict__ WuT)
{
    int t = blockIdx.x * 256 + threadIdx.x;
    if (t < 65536) {
        int j = t >> 10, i = t & 1023;
        int i1 = i >> 7, i2 = (i >> 3) & 15, i3 = i & 7;
        int j1 = j >> 4, j2 = (j >> 2) & 3, j3 = j & 3;
        float t3[8];
#pragma unroll
        for (int b = 0; b < 8; ++b) t3[b] = d3[(b * 8 + i3) * 4 + j3];
        float wsum = 0.f;
#pragma unroll
        for (int a = 0; a < 8; ++a) {
            float va = d1[(i1 * 4 + j1) * 8 + a];
            const float* p2 = d2 + ((a * 16 + i2) * 4 + j2) * 8;
            float wa = 0.f;
#pragma unroll
            for (int b = 0; b < 8; ++b) wa = fmaf(p2[b], t3[b], wa);
            wsum = fmaf(va, wa, wsum);
        }
        WdT[j * 1024 + i] = f2bf(wsum);
    } else {
        int t2 = t - 65536;
        int d = t2 >> 6, k = t2 & 63;
        int k1 = k >> 4, k2 = (k >> 2) & 3, k3 = k & 3;
        int o1 = d >> 7, o2 = (d >> 3) & 15, o3 = d & 7;
        float t3[8];
#pragma unroll
        for (int b = 0; b < 8; ++b) t3[b] = u3[(b * 4 + k3) * 8 + o3];
        float wsum = 0.f;
#pragma unroll
        for (int a = 0; a < 8; ++a) {
            float va = u1[(k1 * 8 + o1) * 8 + a];
            const float* p2 = u2 + ((a * 4 + k2) * 16 + o2) * 8;
            float wa = 0.f;
#pragma unroll
            for (int b = 0; b < 8; ++b) wa = fmaf(p2[b], t3[b], wa);
            wsum = fmaf(va, wa, wsum);
        }
        WuT[d * 64 + k] = f2bf(wsum);
    }
}

// ---------------------------------------------------------------------------
// Fused main kernel, m97-style staging. 1024 blocks x 256 thr (4 waves).
// Block = one 16-row tile.
//   1) stage x tile (16 x 1024 f32) -> LDS via 16 global_load_lds per wave
//      (fire-and-forget; single drain at the barrier). Rows padded to 1028
//      f32: ds_read_b128 at (l15,kg) starts 4*(l15+2kg) mod 32 -> all 32
//      banks busy every phase (conflict-free minimum); 16B-aligned dests.
//   2) phase A: wave w owns K quarter [256w,+256): 8 steps of
//      {2 ds_read_b128 (x), 4 WdT short8 L2 loads, cvt, 4 MFMA} --
//      compiler-scheduled (m97: its fine-grained waitcnts are near-optimal).
//   3) red[4][1024] ALIASED into x-LDS (x fully consumed; barriers guard).
//      r2/r4-verified conflict-free reduce + bias + relu -> bf16 zlds.
//   4) phase B (r4-verified swapped MFMA): 16 col-tiles of {2 WuT loads,
//      2 MFMA, bias} -> dwordx4 y stores, fire-and-forget.
// LDS = 65792(x/red) + 2560(z) = 68 KB -> 2 blocks/CU ping-pong.
// ---------------------------------------------------------------------------
__global__ __launch_bounds__(256) void tt_fused_kernel(
    const float* __restrict__ x, const unsigned short* __restrict__ WdT,
    const unsigned short* __restrict__ WuT, const float* __restrict__ bd,
    const float* __restrict__ bu, float* __restrict__ y)
{
    __shared__ float xf[16 * 1028];            // x tile; later aliased as red
    __shared__ unsigned short zlds[16 * 80];   // z bf16, stride 80
    const int t = threadIdx.x;
    const int lane = t & 63;
    const int w = t >> 6;          // 0..3
    const int l15 = lane & 15;
    const int kg = lane >> 4;      // 0..3
    const int tile = blockIdx.x;
    const int rb = tile * 16;

    // ---- 1) stage: wave w loads rows [4w, 4w+4), 4 chunks of 1 KB each ----
    {
        const int r0 = w * 4;
#pragma unroll
        for (int rr = 0; rr < 4; ++rr) {
            const float* gr = x + (size_t)(rb + r0 + rr) * 1024 + lane * 4;
            float* lr = xf + (r0 + rr) * 1028;
#pragma unroll
            for (int c = 0; c < 4; ++c)
                gload_lds16(gr + c * 256, lr + c * 256);
        }
    }
    __syncthreads();

    // ---- 2) phase A: z-partials over wave's K quarter ---------------------
    const int kb = w * 256;
    f32x4 acc[4] = {{0.f, 0.f, 0.f, 0.f}, {0.f, 0.f, 0.f, 0.f},
                    {0.f, 0.f, 0.f, 0.f}, {0.f, 0.f, 0.f, 0.f}};
    const unsigned short* wp = WdT + l15 * 1024 + kb + kg * 8;
    const float* xrow = xf + l15 * 1028 + kb + kg * 8;
#pragma unroll
    for (int ks = 0; ks < 8; ++ks) {
        f32x4 x0 = *reinterpret_cast<const f32x4*>(xrow + ks * 32);
        f32x4 x1 = *reinterpret_cast<const f32x4*>(xrow + ks * 32 + 4);
        short8 b0 = *reinterpret_cast<const short8*>(wp + 0 * 16384 + ks * 32);
        short8 b1 = *reinterpret_cast<const short8*>(wp + 1 * 16384 + ks * 32);
        short8 b2 = *reinterpret_cast<const short8*>(wp + 2 * 16384 + ks * 32);
        short8 b3 = *reinterpret_cast<const short8*>(wp + 3 * 16384 + ks * 32);
        union { short8 v; unsigned short e[8]; } a;
        a.e[0] = f2bf(x0[0]); a.e[1] = f2bf(x0[1]);
        a.e[2] = f2bf(x0[2]); a.e[3] = f2bf(x0[3]);
        a.e[4] = f2bf(x1[0]); a.e[5] = f2bf(x1[1]);
        a.e[6] = f2bf(x1[2]); a.e[7] = f2bf(x1[3]);
        acc[0] = __builtin_amdgcn_mfma_f32_16x16x32_bf16(a.v, b0, acc[0], 0, 0, 0);
        acc[1] = __builtin_amdgcn_mfma_f32_16x16x32_bf16(a.v, b1, acc[1], 0, 0, 0);
        acc[2] = __builtin_amdgcn_mfma_f32_16x16x32_bf16(a.v, b2, acc[2], 0, 0, 0);
        acc[3] = __builtin_amdgcn_mfma_f32_16x16x32_bf16(a.v, b3, acc[3], 0, 0, 0);
    }
    __syncthreads();   // all waves done reading xf -> safe to alias as red

    // ---- 3) red (aliased) + 4-way reduce + bias + relu -> zlds ------------
    float* red = xf;   // red[wv][i] = xf[wv*1024 + i]
#pragma unroll
    for (int ct = 0; ct < 4; ++ct)
        *reinterpret_cast<f32x4*>(&red[w * 1024 + ct * 256 + lane * 4]) = acc[ct];
    __syncthreads();
    {
        f32x4 v0 = *reinterpret_cast<const f32x4*>(&red[0 * 1024 + t * 4]);
        f32x4 v1 = *reinterpret_cast<const f32x4*>(&red[1 * 1024 + t * 4]);
        f32x4 v2 = *reinterpret_cast<const f32x4*>(&red[2 * 1024 + t * 4]);
        f32x4 v3 = *reinterpret_cast<const f32x4*>(&red[3 * 1024 + t * 4]);
        int colz = (t >> 6) * 16 + (t & 15);
        int rowz = ((t & 63) >> 4) * 4;
        float bdv = bd[colz];
#pragma unroll
        for (int r = 0; r < 4; ++r) {
            float zz = v0[r] + v1[r] + v2[r] + v3[r] + bdv;
            zz = zz > 0.f ? zz : 0.f;
            zlds[(rowz + r) * 80 + colz] = f2bf(zz);
        }
    }
    __syncthreads();

    // ---- 4) phase B: y^T-tile = WuT-frag x z-frag -> dwordx4 stores -------
    short8 az0 = *reinterpret_cast<const short8*>(zlds + l15 * 80 + kg * 8);
    short8 az1 = *reinterpret_cast<const short8*>(zlds + l15 * 80 + 32 + kg * 8);
    const size_t yb = (size_t)(rb + l15) * 1024;
#pragma unroll 4
    for (int i = 0; i < 16; ++i) {
        const int dbase = w * 256 + i * 16;
        const unsigned short* wup = WuT + (dbase + l15) * 64 + kg * 8;
        short8 a0 = *reinterpret_cast<const short8*>(wup);
        short8 a1 = *reinterpret_cast<const short8*>(wup + 32);
        f32x4 c = {0.f, 0.f, 0.f, 0.f};
        c = __builtin_amdgcn_mfma_f32_16x16x32_bf16(a0, az0, c, 0, 0, 0);
        c = __builtin_amdgcn_mfma_f32_16x16x32_bf16(a1, az1, c, 0, 0, 0);
        f32x4 bv = *reinterpret_cast<const f32x4*>(bu + dbase + kg * 4);
        f32x4 o;
#pragma unroll
        for (int r = 0; r < 4; ++r) o[r] = c[r] + bv[r];
        // lane holds y[rb+l15][dbase + kg*4 + r], r contiguous -> dwordx4
        *reinterpret_cast<f32x4*>(y + yb + dbase + kg * 4) = o;
    }
}

extern "C" void kernel_launch(void* const* d_in, const int* in_sizes, int n_in,
                              void* d_out, int out_size, void* d_ws, size_t ws_size,
                              hipStream_t stream) {
    const float* x  = (const float*)d_in[0];
    const float* d1 = (const float*)d_in[1];
    const float* d2 = (const float*)d_in[2];
    const float* d3 = (const float*)d_in[3];
    const float* u1 = (const float*)d_in[4];
    const float* u2 = (const float*)d_in[5];
    const float* u3 = (const float*)d_in[6];
    const float* bd = (const float*)d_in[7];
    const float* bu = (const float*)d_in[8];
    float* y = (float*)d_out;
    unsigned short* WdT = (unsigned short*)d_ws;   // 64x1024 bf16 (128 KB)
    unsigned short* WuT = WdT + 65536;             // 1024x64 bf16 (128 KB)

    hipLaunchKernelGGL(tt_build_w_kernel, dim3(512), dim3(256), 0, stream,
                       d1, d2, d3, u1, u2, u3, WdT, WuT);
    hipLaunchKernelGGL(tt_fused_kernel, dim3(1024), dim3(256), 0, stream,
                       x, WdT, WuT, bd, bu, y);
}